// Round 19
// baseline (178.669 us; speedup 1.0000x reference)
//
#include <hip/hip_runtime.h>
#include <math.h>

#define B_ 16
#define H_ 512
#define L_ 2048
#define N_ 64
#define CD_ 128
#define KSTRIDE 2112   // u16 per Krv row (2048 + 64 zero pad)

typedef unsigned int u32;
typedef unsigned short u16;
typedef __attribute__((ext_vector_type(8))) short bf16x8;   // 8 bf16 in 4 VGPRs
typedef __attribute__((ext_vector_type(4))) float f32x4;    // mfma 16x16x32 C/D

__device__ __forceinline__ float gelu_f(float v) {
    return 0.5f * v * (1.0f + erff(v * 0.70710678118654752f));
}
__device__ __forceinline__ float bf2f(u16 b) {
    union { u32 u; float f; } c; c.u = ((u32)b) << 16; return c.f;
}
__device__ __forceinline__ u16 f2bf(float f) {
    union { float f; u32 u; } c; c.f = f;
    u32 u = c.u;
    return (u16)((u + 0x7FFFu + ((u >> 16) & 1u)) >> 16);
}
// HW packed f32->bf16 (RTNE), 1 instr for 2 values: lo=a, hi=b
__device__ __forceinline__ u32 pack2(float a, float b) {
    u32 r;
    asm("v_cvt_pk_bf16_f32 %0, %1, %2" : "=v"(r) : "v"(a), "v"(b));
    return r;
}
__device__ __forceinline__ float2 cmul(float2 a, float2 b) {
    return make_float2(a.x * b.x - a.y * b.y, a.x * b.y + a.y * b.x);
}

// ---------------------------------------------------------------- sentinel fill
__global__ void k_fill(float* __restrict__ out, int n, float val) {
    int i = blockIdx.x * 256 + threadIdx.x;
    if (i < n) out[i] = val;
}

// ---------------------------------------------------------------- W -> bf16 (one-time)
__global__ __launch_bounds__(128) void k_prepW(const float* __restrict__ W,
                                               u16* __restrict__ Wb) {
    int g = blockIdx.x, t = threadIdx.x;
    float4 v = ((const float4*)(W + (size_t)g * H_))[t];
    u32* dst = (u32*)(Wb + (size_t)g * H_);
    dst[t * 2]     = pack2(v.x, v.y);
    dst[t * 2 + 1] = pack2(v.z, v.w);
}

// ---------------------------------------------------------------- x -> bf16 transposed: xT[b][l][k]
__global__ __launch_bounds__(256) void k_prepX(const float* __restrict__ x,
                                               u16* __restrict__ xT) {
    int b  = blockIdx.z;
    int k0 = blockIdx.y * 64;
    int l0 = blockIdx.x * 256;
    __shared__ float xs[64][260];
    int t = threadIdx.x;
    int cr = t >> 6;            // 0..3
    int cc = (t & 63) * 4;
    #pragma unroll
    for (int p = 0; p < 16; ++p) {
        int r = p * 4 + cr;
        float4 v = *(const float4*)&x[((size_t)b * H_ + k0 + r) * L_ + l0 + cc];
        xs[r][cc] = v.x; xs[r][cc + 1] = v.y; xs[r][cc + 2] = v.z; xs[r][cc + 3] = v.w;
    }
    __syncthreads();
    // thread t owns output row l = l0 + t (column read, conflict-free via 260 pitch)
    u16* dst = xT + ((size_t)b * L_ + l0 + t) * H_ + k0;
    #pragma unroll
    for (int j = 0; j < 8; ++j) {
        uint4 w;
        w.x = pack2(xs[j * 8 + 0][t], xs[j * 8 + 1][t]);
        w.y = pack2(xs[j * 8 + 2][t], xs[j * 8 + 3][t]);
        w.z = pack2(xs[j * 8 + 4][t], xs[j * 8 + 5][t]);
        w.w = pack2(xs[j * 8 + 6][t], xs[j * 8 + 7][t]);
        *(uint4*)&dst[j * 8] = w;
    }
}

// ---------------------------------------------------------------- K via power tables -> reversed bf16
__global__ __launch_bounds__(256) void k_K4(
    const float* __restrict__ log_dt, const float* __restrict__ C_ri,
    const float* __restrict__ log_A_real, const float* __restrict__ A_imag,
    u16* __restrict__ Krv) {
    int h = blockIdx.x, t = threadIdx.x;
    __shared__ float2 P1[N_][8], P8[N_][4], P32[N_][8], P256[N_][8], Cs[N_];
    if (t < N_) {
        int n = t;
        float dt = expf(log_dt[h]);
        float a_re = -expf(log_A_real[h * N_ + n]);
        float a_im = A_imag[h * N_ + n];
        float dre = a_re * dt, dim = a_im * dt;
        float er = expf(dre);
        float s, c;
        sincosf(dim, &s, &c);
        float2 E1 = make_float2(er * c, er * s);
        float num_re = E1.x - 1.0f, num_im = E1.y;
        float den = a_re * a_re + a_im * a_im;
        float q_re = (num_re * a_re + num_im * a_im) / den;
        float q_im = (num_im * a_re - num_re * a_im) / den;
        float Cr = C_ri[(h * N_ + n) * 2 + 0], Ci = C_ri[(h * N_ + n) * 2 + 1];
        Cs[n] = make_float2(Cr * q_re - Ci * q_im, Cr * q_im + Ci * q_re);
        float2 w = make_float2(1.f, 0.f);
        #pragma unroll
        for (int i = 0; i < 8; ++i) { P1[n][i] = w; w = cmul(w, E1); }
        float2 E8 = w; w = make_float2(1.f, 0.f);
        #pragma unroll
        for (int i = 0; i < 4; ++i) { P8[n][i] = w; w = cmul(w, E8); }
        float2 E32 = w; w = make_float2(1.f, 0.f);
        #pragma unroll
        for (int i = 0; i < 8; ++i) { P32[n][i] = w; w = cmul(w, E32); }
        float2 E256 = w; w = make_float2(1.f, 0.f);
        #pragma unroll
        for (int i = 0; i < 8; ++i) { P256[n][i] = w; w = cmul(w, E256); }
    }
    __syncthreads();
    int qh = t >> 5, ql = (t >> 2) & 7, rh = t & 3;
    float acc[8] = {};
    for (int n = 0; n < N_; ++n) {
        float2 a = cmul(Cs[n], P256[n][qh]);
        a = cmul(a, P32[n][ql]);
        a = cmul(a, P8[n][rh]);
        #pragma unroll
        for (int j = 0; j < 8; ++j) {
            float2 e = P1[n][j];
            acc[j] += a.x * e.x - a.y * e.y;
        }
    }
    u16* Krow = Krv + (size_t)h * KSTRIDE;
    uint4 w4;
    w4.x = pack2(2.0f * acc[7], 2.0f * acc[6]);
    w4.y = pack2(2.0f * acc[5], 2.0f * acc[4]);
    w4.z = pack2(2.0f * acc[3], 2.0f * acc[2]);
    w4.w = pack2(2.0f * acc[1], 2.0f * acc[0]);
    *(uint4*)&Krow[2040 - 8 * t] = w4;
    if (t < 8) {
        uint4 z = {0u, 0u, 0u, 0u};
        *(uint4*)&Krow[2048 + 8 * t] = z;
    }
}

// ---------------------------------------------------------------- linear v8: both operands bf16, pass-through staging
__global__ __launch_bounds__(512, 4) void k_linear8(
    const u16* __restrict__ xT, const u16* __restrict__ Wb,
    const float* __restrict__ bias, u16* __restrict__ hb16) {
    int b  = blockIdx.z;
    int g0 = blockIdx.y * 128;
    int l0 = blockIdx.x * 128;
    __shared__ __align__(16) char sm[32768];     // Wp 16K | Xl 16K ; epilogue: Yt 32K
    u16* Wp = (u16*)sm;
    u16* Xl = (u16*)(sm + 16384);
    int t = threadIdx.x;
    int lane = t & 63, wv = t >> 6;
    int n = lane & 15, kg = lane >> 4;
    int wr = wv >> 2, wc = wv & 3;
    int wrow = t >> 2, woct = t & 3;       // staging: row, 16B-oct pair base

    f32x4 acc[4][2];
    #pragma unroll
    for (int m = 0; m < 4; ++m)
        #pragma unroll
        for (int q = 0; q < 2; ++q) acc[m][q] = (f32x4){0.f, 0.f, 0.f, 0.f};

    const u32* wsrc = (const u32*)(Wb + (size_t)(g0 + wrow) * H_);
    const u32* xsrc = (const u32*)(xT + ((size_t)b * L_ + l0 + wrow) * H_);

    uint4 cwq[2], cxq[2], nwq[2], nxq[2];
    #pragma unroll
    for (int j = 0; j < 2; ++j) {
        cwq[j] = *(const uint4*)&wsrc[(woct * 2 + j) * 4];
        cxq[j] = *(const uint4*)&xsrc[(woct * 2 + j) * 4];
    }

    #pragma unroll
    for (int S = 0; S < 8; ++S) {
        if (S) __syncthreads();            // barrier A: prev frag reads done
        #pragma unroll
        for (int j = 0; j < 2; ++j) {
            int oct = woct * 2 + j;
            u32 off = (u32)(wrow * 128 + ((oct * 16) ^ ((wrow & 7) << 4)));
            *(uint4*)((char*)Wp + off) = cwq[j];
            *(uint4*)((char*)Xl + off) = cxq[j];
        }
        __syncthreads();                   // barrier B: tiles ready
        if (S < 7) {                       // prefetch next step (4 uint4s, 16 VGPRs)
            int kn = (S + 1) * 32;         // u32 index = 64 u16
            #pragma unroll
            for (int j = 0; j < 2; ++j) {
                nwq[j] = *(const uint4*)&wsrc[kn + (woct * 2 + j) * 4];
                nxq[j] = *(const uint4*)&xsrc[kn + (woct * 2 + j) * 4];
            }
        }
        #pragma unroll
        for (int ks = 0; ks < 2; ++ks) {
            bf16x8 af[4], bfr[2];
            #pragma unroll
            for (int m = 0; m < 4; ++m) {
                int row = wr * 64 + m * 16 + n;
                af[m] = *(const bf16x8*)((const char*)Wp + row * 128 +
                         ((ks * 64 + kg * 16) ^ ((row & 7) << 4)));
            }
            #pragma unroll
            for (int q = 0; q < 2; ++q) {
                int row = wc * 32 + q * 16 + n;
                bfr[q] = *(const bf16x8*)((const char*)Xl + row * 128 +
                          ((ks * 64 + kg * 16) ^ ((row & 7) << 4)));
            }
            #pragma unroll
            for (int m = 0; m < 4; ++m)
                #pragma unroll
                for (int q = 0; q < 2; ++q)
                    acc[m][q] = __builtin_amdgcn_mfma_f32_16x16x32_bf16(
                        af[m], bfr[q], acc[m][q], 0, 0, 0);
        }
        if (S < 7) {
            cwq[0] = nwq[0]; cwq[1] = nwq[1];
            cxq[0] = nxq[0]; cxq[1] = nxq[1];
        }
    }

    // ---- epilogue: bounce through LDS, then fully-coalesced uint4 stores
    __syncthreads();
    u16* Yt = (u16*)sm;                    // [128 g][128 l] bf16 = 32 KB
    #pragma unroll
    for (int m = 0; m < 4; ++m) {
        #pragma unroll
        for (int r = 0; r < 4; ++r) {
            int grow = wr * 64 + m * 16 + kg * 4 + r;
            float bi = bias[g0 + grow];
            float v0 = gelu_f(acc[m][0][r] + bi);
            float v1 = gelu_f(acc[m][1][r] + bi);
            u32 pr = pack2(v0, v1);
            Yt[grow * 128 + wc * 32 + n]      = (u16)(pr & 0xFFFFu);
            Yt[grow * 128 + wc * 32 + 16 + n] = (u16)(pr >> 16);
        }
    }
    __syncthreads();
    int rrow = t >> 4, c16 = t & 15;
    #pragma unroll
    for (int pass = 0; pass < 4; ++pass) {
        int row = rrow + 32 * pass;
        uint4 v = *(const uint4*)&Yt[row * 128 + c16 * 8];
        *(uint4*)&hb16[((size_t)b * H_ + g0 + row) * L_ + l0 + c16 * 8] = v;
    }
}

// ---------------------------------------------------------------- conv band step (templated, statically renamed ring)
template<int E, bool DIAG, bool TAIL, bool LOAD>
__device__ __forceinline__ void cstep(const uint2* __restrict__ KD2, int& base,
    bf16x8 (&ring)[8], f32x4 (&accR)[8], const char* smem,
    int rowbase, u32 swz, int kg16, int& ja) {
    uint2 w01, w23;
    if (DIAG) {
        int b0 = base < 2047 ? base : 2047;
        int b1 = (base + 4) < 2047 ? (base + 4) : 2047;
        w01 = KD2[b0];
        w23 = KD2[b1];
        if (base > 2047)     { w01.x = 0u; w01.y = 0u; }
        if (base + 4 > 2047) { w23.x = 0u; w23.y = 0u; }
    } else {
        w01 = KD2[base];
        w23 = KD2[base + 4];
    }
    union { u32 u[4]; bf16x8 v; } bu;
    bu.u[0] = w01.x; bu.u[1] = w01.y; bu.u[2] = w23.x; bu.u[3] = w23.y;
    #pragma unroll
    for (int m = 0; m < 8; ++m)
        if (!TAIL || m >= E)
            accR[m] = __builtin_amdgcn_mfma_f32_16x16x32_bf16(
                ring[(m - E) & 7], bu.v, accR[m], 0, 0, 0);
    if (LOAD) {
        ring[(7 - E) & 7] = *(const bf16x8*)(smem + rowbase +
                            (((u32)(ja * 64 + kg16)) ^ swz));
        ja -= 1;
    }
    base -= 32;
}

template<bool DIAG, bool TAIL, bool LOAD>
__device__ __forceinline__ void cblock8(const uint2* __restrict__ KD2, int& base,
    bf16x8 (&ring)[8], f32x4 (&accR)[8], const char* smem,
    int rowbase, u32 swz, int kg16, int& ja) {
    cstep<0, DIAG,  TAIL, LOAD>(KD2, base, ring, accR, smem, rowbase, swz, kg16, ja);
    cstep<1, false, TAIL, LOAD>(KD2, base, ring, accR, smem, rowbase, swz, kg16, ja);
    cstep<2, false, TAIL, LOAD>(KD2, base, ring, accR, smem, rowbase, swz, kg16, ja);
    cstep<3, false, TAIL, LOAD>(KD2, base, ring, accR, smem, rowbase, swz, kg16, ja);
    cstep<4, false, TAIL, LOAD>(KD2, base, ring, accR, smem, rowbase, swz, kg16, ja);
    cstep<5, false, TAIL, LOAD>(KD2, base, ring, accR, smem, rowbase, swz, kg16, ja);
    cstep<6, false, TAIL, LOAD>(KD2, base, ring, accR, smem, rowbase, swz, kg16, ja);
    cstep<7, false, TAIL, LOAD>(KD2, base, ring, accR, smem, rowbase, swz, kg16, ja);
}

// ---------------------------------------------------------------- conv v5: band MFMA + LDS-bounce epilogue
__global__ __launch_bounds__(512, 4) void k_conv_mfma(
    float* __restrict__ out, const u16* __restrict__ hb16,
    const u16* __restrict__ Krv, const float* __restrict__ Dp,
    const float* __restrict__ x, const float* __restrict__ cond,
    const float* __restrict__ film_w, const float* __restrict__ film_b,
    const float* __restrict__ res_w) {
    int g = blockIdx.x;
    __shared__ __align__(16) char smem[81920];   // Hs 64KB + KD2 16KB (red/film aliased)
    uint2* KD2 = (uint2*)(smem + 65536);         // 2048 entries
    int t = threadIdx.x;
    int wv = t >> 6, lane = t & 63;
    int n = lane & 15, kg = lane >> 4;

    {
        const u16* Krow = Krv + (size_t)g * KSTRIDE;
        uint2 d0 = *(const uint2*)&Krow[4 * t];
        uint2 d1 = *(const uint2*)&Krow[4 * t + 4];
        u32 m12 = (d0.x >> 16) | (d0.y << 16);
        u32 m34 = (d0.y >> 16) | (d1.x << 16);
        u32 m56 = (d1.x >> 16) | (d1.y << 16);
        uint4 e01 = {d0.x, d0.y, m12, m34};
        uint4 e23 = {d0.y, d1.x, m34, m56};
        *(uint4*)&KD2[4 * t]     = e01;
        *(uint4*)&KD2[4 * t + 2] = e23;
    }
    #pragma unroll
    for (int b = 0; b < B_; ++b) {
        uint2 p2 = *(const uint2*)&hb16[((size_t)b * H_ + g) * L_ + t * 4];
        *(uint2*)(smem + b * 4096 + (((u32)(t * 8)) ^ ((b & 7) << 4))) = p2;
    }
    __syncthreads();

    const int p = wv & 1, q4 = wv >> 1;
    const int rowbase = n * 4096;
    const u32 swz = (u32)((n & 7) << 4);
    const int kg16 = kg * 16;
    const int bofs = 8 * kg - n;
    const int rrs[2] = {q4, 7 - q4};

    f32x4 acc[2][8];
    #pragma unroll
    for (int ri = 0; ri < 2; ++ri)
        #pragma unroll
        for (int m = 0; m < 8; ++m) acc[ri][m] = (f32x4){0.f, 0.f, 0.f, 0.f};

    #pragma unroll
    for (int ri = 0; ri < 2; ++ri) {
        const int rr = rrs[ri];
        const int k8 = rr * 8;
        bf16x8 ring[8];
        #pragma unroll
        for (int m = 0; m < 8; ++m)
            ring[m] = *(const bf16x8*)(smem + rowbase +
                      (((u32)((k8 + m) * 64 + kg16)) ^ swz));
        int base = 2047 - 16 * p + bofs;
        int ja = k8 - 1;
        if (rr == 0) {
            cblock8<true, true, false>(KD2, base, ring, acc[ri], smem, rowbase, swz, kg16, ja);
        } else {
            cblock8<true, false, true>(KD2, base, ring, acc[ri], smem, rowbase, swz, kg16, ja);
            for (int bi = 1; bi < rr; ++bi)
                cblock8<false, false, true>(KD2, base, ring, acc[ri], smem, rowbase, swz, kg16, ja);
            cblock8<false, true, false>(KD2, base, ring, acc[ri], smem, rowbase, swz, kg16, ja);
        }
    }

    // ---- phase 2: y = conv + D*h ; stats ; y (bf16) back into Hs slots
    __syncthreads();
    float Dg = Dp[g];
    float sum = 0.f, sq = 0.f;
    #pragma unroll
    for (int ri = 0; ri < 2; ++ri) {
        #pragma unroll
        for (int m = 0; m < 8; ++m) {
            const int l0 = 16 * p + 256 * rrs[ri] + 32 * m;
            #pragma unroll
            for (int r = 0; r < 4; ++r) {
                int b = kg * 4 + r;
                u32 hoff = ((u32)(2 * (l0 + n))) ^ ((u32)((b & 7) << 4));
                float hval = bf2f(*(const u16*)(smem + b * 4096 + hoff));
                float y = acc[ri][m][r] + Dg * hval;
                sum += y; sq += y * y;
                *(u16*)(smem + b * 4096 + hoff) = f2bf(y);
            }
        }
    }
    #pragma unroll
    for (int off = 32; off > 0; off >>= 1) {
        sum += __shfl_down(sum, off);
        sq  += __shfl_down(sq, off);
    }
    __syncthreads();
    float* red = (float*)(smem + 65536);
    if (lane == 0) { red[wv] = sum; red[8 + wv] = sq; }
    if (t >= 64 && t < 96) {
        int tid = t - 64, b = tid >> 1, which = tid & 1;
        int row = which ? (H_ + g) : g;
        float a = film_b[row];
        const float4* wr4 = (const float4*)(film_w + (size_t)row * CD_);
        const float4* cp4 = (const float4*)(cond + b * CD_);
        #pragma unroll
        for (int c4 = 0; c4 < CD_ / 4; ++c4) {
            float4 cw = cp4[c4], ww = wr4[c4];
            a += cw.x * ww.x + cw.y * ww.y + cw.z * ww.z + cw.w * ww.w;
        }
        red[18 + tid] = a;
    }
    __syncthreads();
    if (t == 0) {
        float s = 0.f, q = 0.f;
        #pragma unroll
        for (int i = 0; i < 8; ++i) { s += red[i]; q += red[8 + i]; }
        const float inv = 1.0f / (float)(B_ * L_);
        float mean = s * inv;
        float var = q * inv - mean * mean;
        red[16] = mean; red[17] = rsqrtf(var + 1e-5f);
    }
    __syncthreads();

    // ---- phase 3: coalesced BN + FiLM + gelu + residual
    const float mean = red[16], rstd = red[17];
    const float rw = res_w[g];
    const int fb = t >> 5, tc = t & 31;
    const float gf = red[18 + 2 * fb];
    const float bb = red[18 + 2 * fb + 1];
    const u32 fswz = (u32)((fb & 7) << 4);
    const char* yrow = smem + fb * 4096;
    const size_t rowoff = ((size_t)fb * H_ + g) * L_;
    #pragma unroll
    for (int i = 0; i < 16; ++i) {
        int l = tc * 4 + 128 * i;
        uint2 yy = *(const uint2*)(yrow + (((u32)(2 * l)) ^ fswz));
        float4 xv = *(const float4*)&x[rowoff + l];
        float4 o;
        o.x = gelu_f((bf2f((u16)(yy.x & 0xFFFFu)) - mean) * rstd * gf + bb) + xv.x * rw;
        o.y = gelu_f((bf2f((u16)(yy.x >> 16))     - mean) * rstd * gf + bb) + xv.y * rw;
        o.z = gelu_f((bf2f((u16)(yy.y & 0xFFFFu)) - mean) * rstd * gf + bb) + xv.z * rw;
        o.w = gelu_f((bf2f((u16)(yy.y >> 16))     - mean) * rstd * gf + bb) + xv.w * rw;
        *(float4*)&out[rowoff + l] = o;
    }
}

// ---------------------------------------------------------------- launch
extern "C" void kernel_launch(void* const* d_in, const int* in_sizes, int n_in,
                              void* d_out, int out_size, void* d_ws, size_t ws_size,
                              hipStream_t stream) {
    const int expect[12] = {16777216, 2048, 262144, 512, 512, 65536,
                            32768, 32768, 512, 131072, 1024, 512};
    bool ok = (n_in == 12);
    if (ok) for (int i = 0; i < 12; ++i) if (in_sizes[i] != expect[i]) ok = false;
    if (!ok) {
        k_fill<<<(out_size + 255) / 256, 256, 0, stream>>>((float*)d_out, out_size, 1000.0f);
        return;
    }
    const size_t sz_Wb  = (size_t)H_ * H_ * 2;          // 0.5 MB
    const size_t sz_Krv = (size_t)H_ * KSTRIDE * 2;     // 2.1 MB
    const size_t sz_h   = (size_t)B_ * H_ * L_ * 2;     // 33.5 MB
    if (ws_size < sz_Wb + sz_Krv + sz_h + 4096) {       // 36.25 MB total (known good)
        k_fill<<<(out_size + 255) / 256, 256, 0, stream>>>((float*)d_out, out_size, 2000.0f);
        return;
    }

    const float* x          = (const float*)d_in[0];
    const float* cond       = (const float*)d_in[1];
    const float* linear_w   = (const float*)d_in[2];
    const float* linear_b   = (const float*)d_in[3];
    const float* log_dt     = (const float*)d_in[4];
    const float* C_ri       = (const float*)d_in[5];
    const float* log_A_real = (const float*)d_in[6];
    const float* A_imag     = (const float*)d_in[7];
    const float* Dp         = (const float*)d_in[8];
    const float* film_w     = (const float*)d_in[9];
    const float* film_b     = (const float*)d_in[10];
    const float* res_w      = (const float*)d_in[11];

    float* outp = (float*)d_out;
    u16*   xT   = (u16*)d_out;   // first 33.5 MB of d_out; consumed before conv overwrites

    char* w = (char*)d_ws;
    u16* Wb   = (u16*)w;  w += sz_Wb;
    u16* Krv  = (u16*)w;  w += sz_Krv;
    u16* hb16 = (u16*)w;

    k_prepW<<<H_, 128, 0, stream>>>(linear_w, Wb);
    dim3 gpx(L_ / 256, H_ / 64, B_);
    k_prepX<<<gpx, 256, 0, stream>>>(x, xT);
    k_K4<<<H_, 256, 0, stream>>>(log_dt, C_ri, log_A_real, A_imag, Krv);
    dim3 gmm(L_ / 128, H_ / 128, B_);
    k_linear8<<<gmm, 512, 0, stream>>>(xT, Wb, linear_b, hb16);
    k_conv_mfma<<<H_, 512, 0, stream>>>(outp, hb16, Krv, Dp, x,
                                        cond, film_w, film_b, res_w);
}

// Round 20
// 133.656 us; speedup vs baseline: 1.3368x; 1.3368x over previous
//
#include <hip/hip_runtime.h>
#include <math.h>

#define B_ 16
#define H_ 512
#define L_ 2048
#define N_ 64
#define CD_ 128
#define KSTRIDE 2112   // u16 per Krv row (2048 + 64 zero pad)

typedef unsigned int u32;
typedef unsigned short u16;
typedef __attribute__((ext_vector_type(8))) short bf16x8;   // 8 bf16 in 4 VGPRs
typedef __attribute__((ext_vector_type(4))) float f32x4;    // mfma 16x16x32 C/D

#define GLOAD_LDS16(gsrc, ldst) \
    __builtin_amdgcn_global_load_lds( \
        (const __attribute__((address_space(1))) u32*)(const void*)(gsrc), \
        (__attribute__((address_space(3))) u32*)(void*)(ldst), 16, 0, 0)

__device__ __forceinline__ float gelu_f(float v) {
    return 0.5f * v * (1.0f + erff(v * 0.70710678118654752f));
}
__device__ __forceinline__ float bf2f(u16 b) {
    union { u32 u; float f; } c; c.u = ((u32)b) << 16; return c.f;
}
__device__ __forceinline__ u16 f2bf(float f) {
    union { float f; u32 u; } c; c.f = f;
    u32 u = c.u;
    return (u16)((u + 0x7FFFu + ((u >> 16) & 1u)) >> 16);
}
// HW packed f32->bf16 (RTNE), 1 instr for 2 values: lo=a, hi=b
__device__ __forceinline__ u32 pack2(float a, float b) {
    u32 r;
    asm("v_cvt_pk_bf16_f32 %0, %1, %2" : "=v"(r) : "v"(a), "v"(b));
    return r;
}
__device__ __forceinline__ float2 cmul(float2 a, float2 b) {
    return make_float2(a.x * b.x - a.y * b.y, a.x * b.y + a.y * b.x);
}

// ---------------------------------------------------------------- sentinel fill
__global__ void k_fill(float* __restrict__ out, int n, float val) {
    int i = blockIdx.x * 256 + threadIdx.x;
    if (i < n) out[i] = val;
}

// ---------------------------------------------------------------- W -> bf16 (one-time)
__global__ __launch_bounds__(128) void k_prepW(const float* __restrict__ W,
                                               u16* __restrict__ Wb) {
    int g = blockIdx.x, t = threadIdx.x;
    float4 v = ((const float4*)(W + (size_t)g * H_))[t];
    u32* dst = (u32*)(Wb + (size_t)g * H_);
    dst[t * 2]     = pack2(v.x, v.y);
    dst[t * 2 + 1] = pack2(v.z, v.w);
}

// ---------------------------------------------------------------- x -> bf16 transposed: xT[b][l][k]
__global__ __launch_bounds__(256) void k_prepX(const float* __restrict__ x,
                                               u16* __restrict__ xT) {
    int b  = blockIdx.z;
    int k0 = blockIdx.y * 64;
    int l0 = blockIdx.x * 256;
    __shared__ float xs[64][260];
    int t = threadIdx.x;
    int cr = t >> 6;            // 0..3
    int cc = (t & 63) * 4;
    #pragma unroll
    for (int p = 0; p < 16; ++p) {
        int r = p * 4 + cr;
        float4 v = *(const float4*)&x[((size_t)b * H_ + k0 + r) * L_ + l0 + cc];
        xs[r][cc] = v.x; xs[r][cc + 1] = v.y; xs[r][cc + 2] = v.z; xs[r][cc + 3] = v.w;
    }
    __syncthreads();
    u16* dst = xT + ((size_t)b * L_ + l0 + t) * H_ + k0;
    #pragma unroll
    for (int j = 0; j < 8; ++j) {
        uint4 w;
        w.x = pack2(xs[j * 8 + 0][t], xs[j * 8 + 1][t]);
        w.y = pack2(xs[j * 8 + 2][t], xs[j * 8 + 3][t]);
        w.z = pack2(xs[j * 8 + 4][t], xs[j * 8 + 5][t]);
        w.w = pack2(xs[j * 8 + 6][t], xs[j * 8 + 7][t]);
        *(uint4*)&dst[j * 8] = w;
    }
}

// ---------------------------------------------------------------- K via power tables -> reversed bf16
__global__ __launch_bounds__(256) void k_K4(
    const float* __restrict__ log_dt, const float* __restrict__ C_ri,
    const float* __restrict__ log_A_real, const float* __restrict__ A_imag,
    u16* __restrict__ Krv) {
    int h = blockIdx.x, t = threadIdx.x;
    __shared__ float2 P1[N_][8], P8[N_][4], P32[N_][8], P256[N_][8], Cs[N_];
    if (t < N_) {
        int n = t;
        float dt = expf(log_dt[h]);
        float a_re = -expf(log_A_real[h * N_ + n]);
        float a_im = A_imag[h * N_ + n];
        float dre = a_re * dt, dim = a_im * dt;
        float er = expf(dre);
        float s, c;
        sincosf(dim, &s, &c);
        float2 E1 = make_float2(er * c, er * s);
        float num_re = E1.x - 1.0f, num_im = E1.y;
        float den = a_re * a_re + a_im * a_im;
        float q_re = (num_re * a_re + num_im * a_im) / den;
        float q_im = (num_im * a_re - num_re * a_im) / den;
        float Cr = C_ri[(h * N_ + n) * 2 + 0], Ci = C_ri[(h * N_ + n) * 2 + 1];
        Cs[n] = make_float2(Cr * q_re - Ci * q_im, Cr * q_im + Ci * q_re);
        float2 w = make_float2(1.f, 0.f);
        #pragma unroll
        for (int i = 0; i < 8; ++i) { P1[n][i] = w; w = cmul(w, E1); }
        float2 E8 = w; w = make_float2(1.f, 0.f);
        #pragma unroll
        for (int i = 0; i < 4; ++i) { P8[n][i] = w; w = cmul(w, E8); }
        float2 E32 = w; w = make_float2(1.f, 0.f);
        #pragma unroll
        for (int i = 0; i < 8; ++i) { P32[n][i] = w; w = cmul(w, E32); }
        float2 E256 = w; w = make_float2(1.f, 0.f);
        #pragma unroll
        for (int i = 0; i < 8; ++i) { P256[n][i] = w; w = cmul(w, E256); }
    }
    __syncthreads();
    int qh = t >> 5, ql = (t >> 2) & 7, rh = t & 3;
    float acc[8] = {};
    for (int n = 0; n < N_; ++n) {
        float2 a = cmul(Cs[n], P256[n][qh]);
        a = cmul(a, P32[n][ql]);
        a = cmul(a, P8[n][rh]);
        #pragma unroll
        for (int j = 0; j < 8; ++j) {
            float2 e = P1[n][j];
            acc[j] += a.x * e.x - a.y * e.y;
        }
    }
    u16* Krow = Krv + (size_t)h * KSTRIDE;
    uint4 w4;
    w4.x = pack2(2.0f * acc[7], 2.0f * acc[6]);
    w4.y = pack2(2.0f * acc[5], 2.0f * acc[4]);
    w4.z = pack2(2.0f * acc[3], 2.0f * acc[2]);
    w4.w = pack2(2.0f * acc[1], 2.0f * acc[0]);
    *(uint4*)&Krow[2040 - 8 * t] = w4;
    if (t < 8) {
        uint4 z = {0u, 0u, 0u, 0u};
        *(uint4*)&Krow[2048 + 8 * t] = z;
    }
}

// ---------------------------------------------------------------- linear v9: m97-structure (global_load_lds width 16)
// 256 thr / 4 waves; wave (wr=wv>>1, wc=wv&1) owns 64g x 64l; acc 4x4.
// Tiles: As [128 g][64 k] bf16 (linear, 128B rows), Xs [128 l][64 k].
__global__ __launch_bounds__(256, 4) void k_linear9(
    const u16* __restrict__ xT, const u16* __restrict__ Wb,
    const float* __restrict__ bias, u16* __restrict__ hb16) {
    int b  = blockIdx.z;
    int g0 = blockIdx.y * 128;
    int l0 = blockIdx.x * 128;
    __shared__ __align__(16) u16 sm[128 * 128];   // 32 KB: As 16K | Xs 16K; epilogue Yt 32K
    u16* As = sm;
    u16* Xs = sm + 8192;
    int t = threadIdx.x;
    int lane = t & 63, wv = t >> 6;
    int n = lane & 15, kg = lane >> 4;
    int wr = wv >> 1, wc = wv & 1;
    int lr8 = lane >> 3, lc8 = lane & 7;   // staging: row-in-segment, 16B col

    f32x4 acc[4][4];
    #pragma unroll
    for (int m = 0; m < 4; ++m)
        #pragma unroll
        for (int q = 0; q < 4; ++q) acc[m][q] = (f32x4){0.f, 0.f, 0.f, 0.f};

    for (int S = 0; S < 8; ++S) {
        int k0 = S * 64;
        // issue 4+4 async global->LDS (1KB per wave per issue; dest wave-uniform)
        #pragma unroll
        for (int i = 0; i < 4; ++i) {
            int s = wv * 4 + i;               // segment 0..15
            int row = s * 8 + lr8;
            const u16* gA = Wb + (size_t)(g0 + row) * H_ + k0 + lc8 * 8;
            const u16* gX = xT + ((size_t)b * L_ + l0 + row) * H_ + k0 + lc8 * 8;
            GLOAD_LDS16(gA, &As[s * 512]);
            GLOAD_LDS16(gX, &Xs[s * 512]);
        }
        __syncthreads();                      // drains vmcnt, tiles ready
        #pragma unroll
        for (int ks = 0; ks < 2; ++ks) {
            bf16x8 af[4], bf[4];
            #pragma unroll
            for (int m = 0; m < 4; ++m)
                af[m] = *(const bf16x8*)&As[(wr * 64 + m * 16 + n) * 64 + ks * 32 + kg * 8];
            #pragma unroll
            for (int q = 0; q < 4; ++q)
                bf[q] = *(const bf16x8*)&Xs[(wc * 64 + q * 16 + n) * 64 + ks * 32 + kg * 8];
            #pragma unroll
            for (int m = 0; m < 4; ++m)
                #pragma unroll
                for (int q = 0; q < 4; ++q)
                    acc[m][q] = __builtin_amdgcn_mfma_f32_16x16x32_bf16(
                        af[m], bf[q], acc[m][q], 0, 0, 0);
        }
        __syncthreads();                      // frag reads done before restage
    }

    // ---- epilogue: bounce through LDS (Yt 32KB), then coalesced uint4 stores
    u16* Yt = sm;
    #pragma unroll
    for (int m = 0; m < 4; ++m) {
        #pragma unroll
        for (int r = 0; r < 4; ++r) {
            int grow = wr * 64 + m * 16 + kg * 4 + r;
            float bi = bias[g0 + grow];
            #pragma unroll
            for (int q = 0; q < 4; ++q) {
                float v = gelu_f(acc[m][q][r] + bi);
                Yt[grow * 128 + wc * 64 + q * 16 + n] = f2bf(v);
            }
        }
    }
    __syncthreads();
    #pragma unroll
    for (int pass = 0; pass < 8; ++pass) {
        int flat = t + 256 * pass;            // 0..2047 uint4s
        int row = flat >> 4, c16 = flat & 15;
        uint4 v = *(const uint4*)&Yt[row * 128 + c16 * 8];
        *(uint4*)&hb16[((size_t)b * H_ + g0 + row) * L_ + l0 + c16 * 8] = v;
    }
}

// ---------------------------------------------------------------- conv band step (templated, statically renamed ring)
template<int E, bool DIAG, bool TAIL, bool LOAD>
__device__ __forceinline__ void cstep(const uint2* __restrict__ KD2, int& base,
    bf16x8 (&ring)[8], f32x4 (&accR)[8], const char* smem,
    int rowbase, u32 swz, int kg16, int& ja) {
    uint2 w01, w23;
    if (DIAG) {
        int b0 = base < 2047 ? base : 2047;
        int b1 = (base + 4) < 2047 ? (base + 4) : 2047;
        w01 = KD2[b0];
        w23 = KD2[b1];
        if (base > 2047)     { w01.x = 0u; w01.y = 0u; }
        if (base + 4 > 2047) { w23.x = 0u; w23.y = 0u; }
    } else {
        w01 = KD2[base];
        w23 = KD2[base + 4];
    }
    union { u32 u[4]; bf16x8 v; } bu;
    bu.u[0] = w01.x; bu.u[1] = w01.y; bu.u[2] = w23.x; bu.u[3] = w23.y;
    #pragma unroll
    for (int m = 0; m < 8; ++m)
        if (!TAIL || m >= E)
            accR[m] = __builtin_amdgcn_mfma_f32_16x16x32_bf16(
                ring[(m - E) & 7], bu.v, accR[m], 0, 0, 0);
    if (LOAD) {
        ring[(7 - E) & 7] = *(const bf16x8*)(smem + rowbase +
                            (((u32)(ja * 64 + kg16)) ^ swz));
        ja -= 1;
    }
    base -= 32;
}

template<bool DIAG, bool TAIL, bool LOAD>
__device__ __forceinline__ void cblock8(const uint2* __restrict__ KD2, int& base,
    bf16x8 (&ring)[8], f32x4 (&accR)[8], const char* smem,
    int rowbase, u32 swz, int kg16, int& ja) {
    cstep<0, DIAG,  TAIL, LOAD>(KD2, base, ring, accR, smem, rowbase, swz, kg16, ja);
    cstep<1, false, TAIL, LOAD>(KD2, base, ring, accR, smem, rowbase, swz, kg16, ja);
    cstep<2, false, TAIL, LOAD>(KD2, base, ring, accR, smem, rowbase, swz, kg16, ja);
    cstep<3, false, TAIL, LOAD>(KD2, base, ring, accR, smem, rowbase, swz, kg16, ja);
    cstep<4, false, TAIL, LOAD>(KD2, base, ring, accR, smem, rowbase, swz, kg16, ja);
    cstep<5, false, TAIL, LOAD>(KD2, base, ring, accR, smem, rowbase, swz, kg16, ja);
    cstep<6, false, TAIL, LOAD>(KD2, base, ring, accR, smem, rowbase, swz, kg16, ja);
    cstep<7, false, TAIL, LOAD>(KD2, base, ring, accR, smem, rowbase, swz, kg16, ja);
}

// ---------------------------------------------------------------- conv v5: band MFMA + LDS-bounce epilogue
__global__ __launch_bounds__(512, 4) void k_conv_mfma(
    float* __restrict__ out, const u16* __restrict__ hb16,
    const u16* __restrict__ Krv, const float* __restrict__ Dp,
    const float* __restrict__ x, const float* __restrict__ cond,
    const float* __restrict__ film_w, const float* __restrict__ film_b,
    const float* __restrict__ res_w) {
    int g = blockIdx.x;
    __shared__ __align__(16) char smem[81920];   // Hs 64KB + KD2 16KB (red/film aliased)
    uint2* KD2 = (uint2*)(smem + 65536);         // 2048 entries
    int t = threadIdx.x;
    int wv = t >> 6, lane = t & 63;
    int n = lane & 15, kg = lane >> 4;

    {
        const u16* Krow = Krv + (size_t)g * KSTRIDE;
        uint2 d0 = *(const uint2*)&Krow[4 * t];
        uint2 d1 = *(const uint2*)&Krow[4 * t + 4];
        u32 m12 = (d0.x >> 16) | (d0.y << 16);
        u32 m34 = (d0.y >> 16) | (d1.x << 16);
        u32 m56 = (d1.x >> 16) | (d1.y << 16);
        uint4 e01 = {d0.x, d0.y, m12, m34};
        uint4 e23 = {d0.y, d1.x, m34, m56};
        *(uint4*)&KD2[4 * t]     = e01;
        *(uint4*)&KD2[4 * t + 2] = e23;
    }
    #pragma unroll
    for (int b = 0; b < B_; ++b) {
        uint2 p2 = *(const uint2*)&hb16[((size_t)b * H_ + g) * L_ + t * 4];
        *(uint2*)(smem + b * 4096 + (((u32)(t * 8)) ^ ((b & 7) << 4))) = p2;
    }
    __syncthreads();

    const int p = wv & 1, q4 = wv >> 1;
    const int rowbase = n * 4096;
    const u32 swz = (u32)((n & 7) << 4);
    const int kg16 = kg * 16;
    const int bofs = 8 * kg - n;
    const int rrs[2] = {q4, 7 - q4};

    f32x4 acc[2][8];
    #pragma unroll
    for (int ri = 0; ri < 2; ++ri)
        #pragma unroll
        for (int m = 0; m < 8; ++m) acc[ri][m] = (f32x4){0.f, 0.f, 0.f, 0.f};

    #pragma unroll
    for (int ri = 0; ri < 2; ++ri) {
        const int rr = rrs[ri];
        const int k8 = rr * 8;
        bf16x8 ring[8];
        #pragma unroll
        for (int m = 0; m < 8; ++m)
            ring[m] = *(const bf16x8*)(smem + rowbase +
                      (((u32)((k8 + m) * 64 + kg16)) ^ swz));
        int base = 2047 - 16 * p + bofs;
        int ja = k8 - 1;
        if (rr == 0) {
            cblock8<true, true, false>(KD2, base, ring, acc[ri], smem, rowbase, swz, kg16, ja);
        } else {
            cblock8<true, false, true>(KD2, base, ring, acc[ri], smem, rowbase, swz, kg16, ja);
            for (int bi = 1; bi < rr; ++bi)
                cblock8<false, false, true>(KD2, base, ring, acc[ri], smem, rowbase, swz, kg16, ja);
            cblock8<false, true, false>(KD2, base, ring, acc[ri], smem, rowbase, swz, kg16, ja);
        }
    }

    // ---- phase 2: y = conv + D*h ; stats ; y (bf16) back into Hs slots
    __syncthreads();
    float Dg = Dp[g];
    float sum = 0.f, sq = 0.f;
    #pragma unroll
    for (int ri = 0; ri < 2; ++ri) {
        #pragma unroll
        for (int m = 0; m < 8; ++m) {
            const int l0 = 16 * p + 256 * rrs[ri] + 32 * m;
            #pragma unroll
            for (int r = 0; r < 4; ++r) {
                int b = kg * 4 + r;
                u32 hoff = ((u32)(2 * (l0 + n))) ^ ((u32)((b & 7) << 4));
                float hval = bf2f(*(const u16*)(smem + b * 4096 + hoff));
                float y = acc[ri][m][r] + Dg * hval;
                sum += y; sq += y * y;
                *(u16*)(smem + b * 4096 + hoff) = f2bf(y);
            }
        }
    }
    #pragma unroll
    for (int off = 32; off > 0; off >>= 1) {
        sum += __shfl_down(sum, off);
        sq  += __shfl_down(sq, off);
    }
    __syncthreads();
    float* red = (float*)(smem + 65536);
    if (lane == 0) { red[wv] = sum; red[8 + wv] = sq; }
    if (t >= 64 && t < 96) {
        int tid = t - 64, b = tid >> 1, which = tid & 1;
        int row = which ? (H_ + g) : g;
        float a = film_b[row];
        const float4* wr4 = (const float4*)(film_w + (size_t)row * CD_);
        const float4* cp4 = (const float4*)(cond + b * CD_);
        #pragma unroll
        for (int c4 = 0; c4 < CD_ / 4; ++c4) {
            float4 cw = cp4[c4], ww = wr4[c4];
            a += cw.x * ww.x + cw.y * ww.y + cw.z * ww.z + cw.w * ww.w;
        }
        red[18 + tid] = a;
    }
    __syncthreads();
    if (t == 0) {
        float s = 0.f, q = 0.f;
        #pragma unroll
        for (int i = 0; i < 8; ++i) { s += red[i]; q += red[8 + i]; }
        const float inv = 1.0f / (float)(B_ * L_);
        float mean = s * inv;
        float var = q * inv - mean * mean;
        red[16] = mean; red[17] = rsqrtf(var + 1e-5f);
    }
    __syncthreads();

    // ---- phase 3: coalesced BN + FiLM + gelu + residual
    const float mean = red[16], rstd = red[17];
    const float rw = res_w[g];
    const int fb = t >> 5, tc = t & 31;
    const float gf = red[18 + 2 * fb];
    const float bb = red[18 + 2 * fb + 1];
    const u32 fswz = (u32)((fb & 7) << 4);
    const char* yrow = smem + fb * 4096;
    const size_t rowoff = ((size_t)fb * H_ + g) * L_;
    #pragma unroll
    for (int i = 0; i < 16; ++i) {
        int l = tc * 4 + 128 * i;
        uint2 yy = *(const uint2*)(yrow + (((u32)(2 * l)) ^ fswz));
        float4 xv = *(const float4*)&x[rowoff + l];
        float4 o;
        o.x = gelu_f((bf2f((u16)(yy.x & 0xFFFFu)) - mean) * rstd * gf + bb) + xv.x * rw;
        o.y = gelu_f((bf2f((u16)(yy.x >> 16))     - mean) * rstd * gf + bb) + xv.y * rw;
        o.z = gelu_f((bf2f((u16)(yy.y & 0xFFFFu)) - mean) * rstd * gf + bb) + xv.z * rw;
        o.w = gelu_f((bf2f((u16)(yy.y >> 16))     - mean) * rstd * gf + bb) + xv.w * rw;
        *(float4*)&out[rowoff + l] = o;
    }
}

// ---------------------------------------------------------------- launch
extern "C" void kernel_launch(void* const* d_in, const int* in_sizes, int n_in,
                              void* d_out, int out_size, void* d_ws, size_t ws_size,
                              hipStream_t stream) {
    const int expect[12] = {16777216, 2048, 262144, 512, 512, 65536,
                            32768, 32768, 512, 131072, 1024, 512};
    bool ok = (n_in == 12);
    if (ok) for (int i = 0; i < 12; ++i) if (in_sizes[i] != expect[i]) ok = false;
    if (!ok) {
        k_fill<<<(out_size + 255) / 256, 256, 0, stream>>>((float*)d_out, out_size, 1000.0f);
        return;
    }
    const size_t sz_Wb  = (size_t)H_ * H_ * 2;          // 0.5 MB
    const size_t sz_Krv = (size_t)H_ * KSTRIDE * 2;     // 2.1 MB
    const size_t sz_h   = (size_t)B_ * H_ * L_ * 2;     // 33.5 MB
    if (ws_size < sz_Wb + sz_Krv + sz_h + 4096) {       // 36.25 MB total (known good)
        k_fill<<<(out_size + 255) / 256, 256, 0, stream>>>((float*)d_out, out_size, 2000.0f);
        return;
    }

    const float* x          = (const float*)d_in[0];
    const float* cond       = (const float*)d_in[1];
    const float* linear_w   = (const float*)d_in[2];
    const float* linear_b   = (const float*)d_in[3];
    const float* log_dt     = (const float*)d_in[4];
    const float* C_ri       = (const float*)d_in[5];
    const float* log_A_real = (const float*)d_in[6];
    const float* A_imag     = (const float*)d_in[7];
    const float* Dp         = (const float*)d_in[8];
    const float* film_w     = (const float*)d_in[9];
    const float* film_b     = (const float*)d_in[10];
    const float* res_w      = (const float*)d_in[11];

    float* outp = (float*)d_out;
    u16*   xT   = (u16*)d_out;   // first 33.5 MB of d_out; consumed before conv overwrites

    char* w = (char*)d_ws;
    u16* Wb   = (u16*)w;  w += sz_Wb;
    u16* Krv  = (u16*)w;  w += sz_Krv;
    u16* hb16 = (u16*)w;

    k_prepW<<<H_, 128, 0, stream>>>(linear_w, Wb);
    dim3 gpx(L_ / 256, H_ / 64, B_);
    k_prepX<<<gpx, 256, 0, stream>>>(x, xT);
    k_K4<<<H_, 256, 0, stream>>>(log_dt, C_ri, log_A_real, A_imag, Krv);
    dim3 gmm(L_ / 128, H_ / 128, B_);
    k_linear9<<<gmm, 256, 0, stream>>>(xT, Wb, linear_b, hb16);
    k_conv_mfma<<<H_, 512, 0, stream>>>(outp, hb16, Krv, Dp, x,
                                        cond, film_w, film_b, res_w);
}

// Round 21
// 128.003 us; speedup vs baseline: 1.3958x; 1.0442x over previous
//
#include <hip/hip_runtime.h>
#include <math.h>

#define B_ 16
#define H_ 512
#define L_ 2048
#define N_ 64
#define CD_ 128
#define KSTRIDE 2112   // u16 per Krv row (2048 + 64 zero pad)

typedef unsigned int u32;
typedef unsigned short u16;
typedef __attribute__((ext_vector_type(8))) short bf16x8;   // 8 bf16 in 4 VGPRs
typedef __attribute__((ext_vector_type(4))) float f32x4;    // mfma 16x16x32 C/D

#define GLOAD_LDS16(gsrc, ldst) \
    __builtin_amdgcn_global_load_lds( \
        (const __attribute__((address_space(1))) u32*)(const void*)(gsrc), \
        (__attribute__((address_space(3))) u32*)(void*)(ldst), 16, 0, 0)

__device__ __forceinline__ float gelu_f(float v) {
    return 0.5f * v * (1.0f + erff(v * 0.70710678118654752f));
}
__device__ __forceinline__ float bf2f(u16 b) {
    union { u32 u; float f; } c; c.u = ((u32)b) << 16; return c.f;
}
__device__ __forceinline__ u16 f2bf(float f) {
    union { float f; u32 u; } c; c.f = f;
    u32 u = c.u;
    return (u16)((u + 0x7FFFu + ((u >> 16) & 1u)) >> 16);
}
// HW packed f32->bf16 (RTNE), 1 instr for 2 values: lo=a, hi=b
__device__ __forceinline__ u32 pack2(float a, float b) {
    u32 r;
    asm("v_cvt_pk_bf16_f32 %0, %1, %2" : "=v"(r) : "v"(a), "v"(b));
    return r;
}
__device__ __forceinline__ float2 cmul(float2 a, float2 b) {
    return make_float2(a.x * b.x - a.y * b.y, a.x * b.y + a.y * b.x);
}

// ---------------------------------------------------------------- sentinel fill
__global__ void k_fill(float* __restrict__ out, int n, float val) {
    int i = blockIdx.x * 256 + threadIdx.x;
    if (i < n) out[i] = val;
}

// ---------------------------------------------------------------- fused prep: prepX [0,1024) | prepW [1024,1280) | K4 [1280,1792)
__global__ __launch_bounds__(256) void k_prep(
    const float* __restrict__ x, u16* __restrict__ xT,
    const float* __restrict__ W, u16* __restrict__ Wb,
    const float* __restrict__ log_dt, const float* __restrict__ C_ri,
    const float* __restrict__ log_A_real, const float* __restrict__ A_imag,
    u16* __restrict__ Krv) {
    __shared__ __align__(16) char pool[64 * 264 * 4];   // 67.6 KB
    int bid = blockIdx.x, t = threadIdx.x;

    if (bid < 1024) {
        // ---------------- prepX: x[b][k][l] f32 -> xT[b][l][k] bf16
        int lblk = bid & 7, kblk = (bid >> 3) & 7, b = bid >> 6;
        int k0 = kblk * 64, l0 = lblk * 256;
        float* xs = (float*)pool;              // [64][264]
        int cr = t >> 6;                       // 0..3
        int cc = (t & 63) * 4;
        #pragma unroll
        for (int p = 0; p < 16; ++p) {
            int r = p * 4 + cr;
            float4 v = *(const float4*)&x[((size_t)b * H_ + k0 + r) * L_ + l0 + cc];
            *(float4*)&xs[r * 264 + cc] = v;
        }
        __syncthreads();
        u16* dst = xT + ((size_t)b * L_ + l0 + t) * H_ + k0;
        #pragma unroll
        for (int j = 0; j < 8; ++j) {
            uint4 w;
            w.x = pack2(xs[(j * 8 + 0) * 264 + t], xs[(j * 8 + 1) * 264 + t]);
            w.y = pack2(xs[(j * 8 + 2) * 264 + t], xs[(j * 8 + 3) * 264 + t]);
            w.z = pack2(xs[(j * 8 + 4) * 264 + t], xs[(j * 8 + 5) * 264 + t]);
            w.w = pack2(xs[(j * 8 + 6) * 264 + t], xs[(j * 8 + 7) * 264 + t]);
            *(uint4*)&dst[j * 8] = w;
        }
    } else if (bid < 1280) {
        // ---------------- prepW: W -> bf16, 2 g-rows per block
        int g = (bid - 1024) * 2 + (t >> 7);
        int c = t & 127;
        float4 v = ((const float4*)(W + (size_t)g * H_))[c];
        u32* dst = (u32*)(Wb + (size_t)g * H_);
        dst[c * 2]     = pack2(v.x, v.y);
        dst[c * 2 + 1] = pack2(v.z, v.w);
    } else {
        // ---------------- K4: power tables -> reversed bf16 K
        int h = bid - 1280;
        float2* P1   = (float2*)pool;              // [64][8]
        float2* P8   = (float2*)(pool + 4096);     // [64][4]
        float2* P32  = (float2*)(pool + 6144);     // [64][8]
        float2* P256 = (float2*)(pool + 10240);    // [64][8]
        float2* Cs   = (float2*)(pool + 14336);    // [64]
        if (t < N_) {
            int n = t;
            float dt = expf(log_dt[h]);
            float a_re = -expf(log_A_real[h * N_ + n]);
            float a_im = A_imag[h * N_ + n];
            float dre = a_re * dt, dim = a_im * dt;
            float er = expf(dre);
            float s, c;
            sincosf(dim, &s, &c);
            float2 E1 = make_float2(er * c, er * s);
            float num_re = E1.x - 1.0f, num_im = E1.y;
            float den = a_re * a_re + a_im * a_im;
            float q_re = (num_re * a_re + num_im * a_im) / den;
            float q_im = (num_im * a_re - num_re * a_im) / den;
            float Cr = C_ri[(h * N_ + n) * 2 + 0], Ci = C_ri[(h * N_ + n) * 2 + 1];
            Cs[n] = make_float2(Cr * q_re - Ci * q_im, Cr * q_im + Ci * q_re);
            float2 w = make_float2(1.f, 0.f);
            #pragma unroll
            for (int i = 0; i < 8; ++i) { P1[n * 8 + i] = w; w = cmul(w, E1); }
            float2 E8 = w; w = make_float2(1.f, 0.f);
            #pragma unroll
            for (int i = 0; i < 4; ++i) { P8[n * 4 + i] = w; w = cmul(w, E8); }
            float2 E32 = w; w = make_float2(1.f, 0.f);
            #pragma unroll
            for (int i = 0; i < 8; ++i) { P32[n * 8 + i] = w; w = cmul(w, E32); }
            float2 E256 = w; w = make_float2(1.f, 0.f);
            #pragma unroll
            for (int i = 0; i < 8; ++i) { P256[n * 8 + i] = w; w = cmul(w, E256); }
        }
        __syncthreads();
        int qh = t >> 5, ql = (t >> 2) & 7, rh = t & 3;
        float acc[8] = {};
        for (int n = 0; n < N_; ++n) {
            float2 a = cmul(Cs[n], P256[n * 8 + qh]);
            a = cmul(a, P32[n * 8 + ql]);
            a = cmul(a, P8[n * 4 + rh]);
            #pragma unroll
            for (int j = 0; j < 8; ++j) {
                float2 e = P1[n * 8 + j];
                acc[j] += a.x * e.x - a.y * e.y;
            }
        }
        u16* Krow = Krv + (size_t)h * KSTRIDE;
        uint4 w4;
        w4.x = pack2(2.0f * acc[7], 2.0f * acc[6]);
        w4.y = pack2(2.0f * acc[5], 2.0f * acc[4]);
        w4.z = pack2(2.0f * acc[3], 2.0f * acc[2]);
        w4.w = pack2(2.0f * acc[1], 2.0f * acc[0]);
        *(uint4*)&Krow[2040 - 8 * t] = w4;
        if (t < 8) {
            uint4 z = {0u, 0u, 0u, 0u};
            *(uint4*)&Krow[2048 + 8 * t] = z;
        }
    }
}

// ---------------------------------------------------------------- linear v9 + XCD-chunked block swizzle
// 256 thr / 4 waves; wave (wr=wv>>1, wc=wv&1) owns 64g x 64l; acc 4x4.
__global__ __launch_bounds__(256, 4) void k_linear9(
    const u16* __restrict__ xT, const u16* __restrict__ Wb,
    const float* __restrict__ bias, u16* __restrict__ hb16) {
    // swizzle: orig%8 = XCD; give each XCD a contiguous work chunk so the
    // 4 g-blocks sharing one xT panel stay on one XCD (panel L2-resident).
    int orig = blockIdx.x;                        // 0..1023
    int wid = (orig & 7) * 128 + (orig >> 3);     // bijective
    int b  = wid >> 6;
    int lg = wid & 63;
    int l0 = (lg >> 2) * 128;
    int g0 = (lg & 3) * 128;
    __shared__ __align__(16) u16 sm[128 * 128];   // 32 KB: As 16K | Xs 16K; epilogue Yt
    u16* As = sm;
    u16* Xs = sm + 8192;
    int t = threadIdx.x;
    int lane = t & 63, wv = t >> 6;
    int n = lane & 15, kg = lane >> 4;
    int wr = wv >> 1, wc = wv & 1;
    int lr8 = lane >> 3, lc8 = lane & 7;

    f32x4 acc[4][4];
    #pragma unroll
    for (int m = 0; m < 4; ++m)
        #pragma unroll
        for (int q = 0; q < 4; ++q) acc[m][q] = (f32x4){0.f, 0.f, 0.f, 0.f};

    for (int S = 0; S < 8; ++S) {
        int k0 = S * 64;
        #pragma unroll
        for (int i = 0; i < 4; ++i) {
            int s = wv * 4 + i;               // segment 0..15
            int row = s * 8 + lr8;
            const u16* gA = Wb + (size_t)(g0 + row) * H_ + k0 + lc8 * 8;
            const u16* gX = xT + ((size_t)b * L_ + l0 + row) * H_ + k0 + lc8 * 8;
            GLOAD_LDS16(gA, &As[s * 512]);
            GLOAD_LDS16(gX, &Xs[s * 512]);
        }
        __syncthreads();
        #pragma unroll
        for (int ks = 0; ks < 2; ++ks) {
            bf16x8 af[4], bf[4];
            #pragma unroll
            for (int m = 0; m < 4; ++m)
                af[m] = *(const bf16x8*)&As[(wr * 64 + m * 16 + n) * 64 + ks * 32 + kg * 8];
            #pragma unroll
            for (int q = 0; q < 4; ++q)
                bf[q] = *(const bf16x8*)&Xs[(wc * 64 + q * 16 + n) * 64 + ks * 32 + kg * 8];
            #pragma unroll
            for (int m = 0; m < 4; ++m)
                #pragma unroll
                for (int q = 0; q < 4; ++q)
                    acc[m][q] = __builtin_amdgcn_mfma_f32_16x16x32_bf16(
                        af[m], bf[q], acc[m][q], 0, 0, 0);
        }
        __syncthreads();
    }

    // ---- epilogue: bounce through LDS (Yt 32KB), then coalesced uint4 stores
    u16* Yt = sm;
    #pragma unroll
    for (int m = 0; m < 4; ++m) {
        #pragma unroll
        for (int r = 0; r < 4; ++r) {
            int grow = wr * 64 + m * 16 + kg * 4 + r;
            float bi = bias[g0 + grow];
            #pragma unroll
            for (int q = 0; q < 4; ++q) {
                float v = gelu_f(acc[m][q][r] + bi);
                Yt[grow * 128 + wc * 64 + q * 16 + n] = f2bf(v);
            }
        }
    }
    __syncthreads();
    #pragma unroll
    for (int pass = 0; pass < 8; ++pass) {
        int flat = t + 256 * pass;            // 0..2047 uint4s
        int row = flat >> 4, c16 = flat & 15;
        uint4 v = *(const uint4*)&Yt[row * 128 + c16 * 8];
        *(uint4*)&hb16[((size_t)b * H_ + g0 + row) * L_ + l0 + c16 * 8] = v;
    }
}

// ---------------------------------------------------------------- conv band step (templated, statically renamed ring)
template<int E, bool DIAG, bool TAIL, bool LOAD>
__device__ __forceinline__ void cstep(const uint2* __restrict__ KD2, int& base,
    bf16x8 (&ring)[8], f32x4 (&accR)[8], const char* smem,
    int rowbase, u32 swz, int kg16, int& ja) {
    uint2 w01, w23;
    if (DIAG) {
        int b0 = base < 2047 ? base : 2047;
        int b1 = (base + 4) < 2047 ? (base + 4) : 2047;
        w01 = KD2[b0];
        w23 = KD2[b1];
        if (base > 2047)     { w01.x = 0u; w01.y = 0u; }
        if (base + 4 > 2047) { w23.x = 0u; w23.y = 0u; }
    } else {
        w01 = KD2[base];
        w23 = KD2[base + 4];
    }
    union { u32 u[4]; bf16x8 v; } bu;
    bu.u[0] = w01.x; bu.u[1] = w01.y; bu.u[2] = w23.x; bu.u[3] = w23.y;
    #pragma unroll
    for (int m = 0; m < 8; ++m)
        if (!TAIL || m >= E)
            accR[m] = __builtin_amdgcn_mfma_f32_16x16x32_bf16(
                ring[(m - E) & 7], bu.v, accR[m], 0, 0, 0);
    if (LOAD) {
        ring[(7 - E) & 7] = *(const bf16x8*)(smem + rowbase +
                            (((u32)(ja * 64 + kg16)) ^ swz));
        ja -= 1;
    }
    base -= 32;
}

template<bool DIAG, bool TAIL, bool LOAD>
__device__ __forceinline__ void cblock8(const uint2* __restrict__ KD2, int& base,
    bf16x8 (&ring)[8], f32x4 (&accR)[8], const char* smem,
    int rowbase, u32 swz, int kg16, int& ja) {
    cstep<0, DIAG,  TAIL, LOAD>(KD2, base, ring, accR, smem, rowbase, swz, kg16, ja);
    cstep<1, false, TAIL, LOAD>(KD2, base, ring, accR, smem, rowbase, swz, kg16, ja);
    cstep<2, false, TAIL, LOAD>(KD2, base, ring, accR, smem, rowbase, swz, kg16, ja);
    cstep<3, false, TAIL, LOAD>(KD2, base, ring, accR, smem, rowbase, swz, kg16, ja);
    cstep<4, false, TAIL, LOAD>(KD2, base, ring, accR, smem, rowbase, swz, kg16, ja);
    cstep<5, false, TAIL, LOAD>(KD2, base, ring, accR, smem, rowbase, swz, kg16, ja);
    cstep<6, false, TAIL, LOAD>(KD2, base, ring, accR, smem, rowbase, swz, kg16, ja);
    cstep<7, false, TAIL, LOAD>(KD2, base, ring, accR, smem, rowbase, swz, kg16, ja);
}

// ---------------------------------------------------------------- conv v5: band MFMA + LDS-bounce epilogue
__global__ __launch_bounds__(512, 4) void k_conv_mfma(
    float* __restrict__ out, const u16* __restrict__ hb16,
    const u16* __restrict__ Krv, const float* __restrict__ Dp,
    const float* __restrict__ x, const float* __restrict__ cond,
    const float* __restrict__ film_w, const float* __restrict__ film_b,
    const float* __restrict__ res_w) {
    int g = blockIdx.x;
    __shared__ __align__(16) char smem[81920];   // Hs 64KB + KD2 16KB (red/film aliased)
    uint2* KD2 = (uint2*)(smem + 65536);         // 2048 entries
    int t = threadIdx.x;
    int wv = t >> 6, lane = t & 63;
    int n = lane & 15, kg = lane >> 4;

    {
        const u16* Krow = Krv + (size_t)g * KSTRIDE;
        uint2 d0 = *(const uint2*)&Krow[4 * t];
        uint2 d1 = *(const uint2*)&Krow[4 * t + 4];
        u32 m12 = (d0.x >> 16) | (d0.y << 16);
        u32 m34 = (d0.y >> 16) | (d1.x << 16);
        u32 m56 = (d1.x >> 16) | (d1.y << 16);
        uint4 e01 = {d0.x, d0.y, m12, m34};
        uint4 e23 = {d0.y, d1.x, m34, m56};
        *(uint4*)&KD2[4 * t]     = e01;
        *(uint4*)&KD2[4 * t + 2] = e23;
    }
    #pragma unroll
    for (int b = 0; b < B_; ++b) {
        uint2 p2 = *(const uint2*)&hb16[((size_t)b * H_ + g) * L_ + t * 4];
        *(uint2*)(smem + b * 4096 + (((u32)(t * 8)) ^ ((b & 7) << 4))) = p2;
    }
    __syncthreads();

    const int p = wv & 1, q4 = wv >> 1;
    const int rowbase = n * 4096;
    const u32 swz = (u32)((n & 7) << 4);
    const int kg16 = kg * 16;
    const int bofs = 8 * kg - n;
    const int rrs[2] = {q4, 7 - q4};

    f32x4 acc[2][8];
    #pragma unroll
    for (int ri = 0; ri < 2; ++ri)
        #pragma unroll
        for (int m = 0; m < 8; ++m) acc[ri][m] = (f32x4){0.f, 0.f, 0.f, 0.f};

    #pragma unroll
    for (int ri = 0; ri < 2; ++ri) {
        const int rr = rrs[ri];
        const int k8 = rr * 8;
        bf16x8 ring[8];
        #pragma unroll
        for (int m = 0; m < 8; ++m)
            ring[m] = *(const bf16x8*)(smem + rowbase +
                      (((u32)((k8 + m) * 64 + kg16)) ^ swz));
        int base = 2047 - 16 * p + bofs;
        int ja = k8 - 1;
        if (rr == 0) {
            cblock8<true, true, false>(KD2, base, ring, acc[ri], smem, rowbase, swz, kg16, ja);
        } else {
            cblock8<true, false, true>(KD2, base, ring, acc[ri], smem, rowbase, swz, kg16, ja);
            for (int bi = 1; bi < rr; ++bi)
                cblock8<false, false, true>(KD2, base, ring, acc[ri], smem, rowbase, swz, kg16, ja);
            cblock8<false, true, false>(KD2, base, ring, acc[ri], smem, rowbase, swz, kg16, ja);
        }
    }

    // ---- phase 2: y = conv + D*h ; stats ; y (bf16) back into Hs slots
    __syncthreads();
    float Dg = Dp[g];
    float sum = 0.f, sq = 0.f;
    #pragma unroll
    for (int ri = 0; ri < 2; ++ri) {
        #pragma unroll
        for (int m = 0; m < 8; ++m) {
            const int l0 = 16 * p + 256 * rrs[ri] + 32 * m;
            #pragma unroll
            for (int r = 0; r < 4; ++r) {
                int b = kg * 4 + r;
                u32 hoff = ((u32)(2 * (l0 + n))) ^ ((u32)((b & 7) << 4));
                float hval = bf2f(*(const u16*)(smem + b * 4096 + hoff));
                float y = acc[ri][m][r] + Dg * hval;
                sum += y; sq += y * y;
                *(u16*)(smem + b * 4096 + hoff) = f2bf(y);
            }
        }
    }
    #pragma unroll
    for (int off = 32; off > 0; off >>= 1) {
        sum += __shfl_down(sum, off);
        sq  += __shfl_down(sq, off);
    }
    __syncthreads();
    float* red = (float*)(smem + 65536);
    if (lane == 0) { red[wv] = sum; red[8 + wv] = sq; }
    if (t >= 64 && t < 96) {
        int tid = t - 64, b = tid >> 1, which = tid & 1;
        int row = which ? (H_ + g) : g;
        float a = film_b[row];
        const float4* wr4 = (const float4*)(film_w + (size_t)row * CD_);
        const float4* cp4 = (const float4*)(cond + b * CD_);
        #pragma unroll
        for (int c4 = 0; c4 < CD_ / 4; ++c4) {
            float4 cw = cp4[c4], ww = wr4[c4];
            a += cw.x * ww.x + cw.y * ww.y + cw.z * ww.z + cw.w * ww.w;
        }
        red[18 + tid] = a;
    }
    __syncthreads();
    if (t == 0) {
        float s = 0.f, q = 0.f;
        #pragma unroll
        for (int i = 0; i < 8; ++i) { s += red[i]; q += red[8 + i]; }
        const float inv = 1.0f / (float)(B_ * L_);
        float mean = s * inv;
        float var = q * inv - mean * mean;
        red[16] = mean; red[17] = rsqrtf(var + 1e-5f);
    }
    __syncthreads();

    // ---- phase 3: coalesced BN + FiLM + gelu + residual
    const float mean = red[16], rstd = red[17];
    const float rw = res_w[g];
    const int fb = t >> 5, tc = t & 31;
    const float gf = red[18 + 2 * fb];
    const float bb = red[18 + 2 * fb + 1];
    const u32 fswz = (u32)((fb & 7) << 4);
    const char* yrow = smem + fb * 4096;
    const size_t rowoff = ((size_t)fb * H_ + g) * L_;
    #pragma unroll
    for (int i = 0; i < 16; ++i) {
        int l = tc * 4 + 128 * i;
        uint2 yy = *(const uint2*)(yrow + (((u32)(2 * l)) ^ fswz));
        float4 xv = *(const float4*)&x[rowoff + l];
        float4 o;
        o.x = gelu_f((bf2f((u16)(yy.x & 0xFFFFu)) - mean) * rstd * gf + bb) + xv.x * rw;
        o.y = gelu_f((bf2f((u16)(yy.x >> 16))     - mean) * rstd * gf + bb) + xv.y * rw;
        o.z = gelu_f((bf2f((u16)(yy.y & 0xFFFFu)) - mean) * rstd * gf + bb) + xv.z * rw;
        o.w = gelu_f((bf2f((u16)(yy.y >> 16))     - mean) * rstd * gf + bb) + xv.w * rw;
        *(float4*)&out[rowoff + l] = o;
    }
}

// ---------------------------------------------------------------- launch
extern "C" void kernel_launch(void* const* d_in, const int* in_sizes, int n_in,
                              void* d_out, int out_size, void* d_ws, size_t ws_size,
                              hipStream_t stream) {
    const int expect[12] = {16777216, 2048, 262144, 512, 512, 65536,
                            32768, 32768, 512, 131072, 1024, 512};
    bool ok = (n_in == 12);
    if (ok) for (int i = 0; i < 12; ++i) if (in_sizes[i] != expect[i]) ok = false;
    if (!ok) {
        k_fill<<<(out_size + 255) / 256, 256, 0, stream>>>((float*)d_out, out_size, 1000.0f);
        return;
    }
    const size_t sz_Wb  = (size_t)H_ * H_ * 2;          // 0.5 MB
    const size_t sz_Krv = (size_t)H_ * KSTRIDE * 2;     // 2.1 MB
    const size_t sz_h   = (size_t)B_ * H_ * L_ * 2;     // 33.5 MB
    if (ws_size < sz_Wb + sz_Krv + sz_h + 4096) {       // 36.25 MB total (known good)
        k_fill<<<(out_size + 255) / 256, 256, 0, stream>>>((float*)d_out, out_size, 2000.0f);
        return;
    }

    const float* x          = (const float*)d_in[0];
    const float* cond       = (const float*)d_in[1];
    const float* linear_w   = (const float*)d_in[2];
    const float* linear_b   = (const float*)d_in[3];
    const float* log_dt     = (const float*)d_in[4];
    const float* C_ri       = (const float*)d_in[5];
    const float* log_A_real = (const float*)d_in[6];
    const float* A_imag     = (const float*)d_in[7];
    const float* Dp         = (const float*)d_in[8];
    const float* film_w     = (const float*)d_in[9];
    const float* film_b     = (const float*)d_in[10];
    const float* res_w      = (const float*)d_in[11];

    float* outp = (float*)d_out;
    u16*   xT   = (u16*)d_out;   // first 33.5 MB of d_out; consumed before conv overwrites

    char* w = (char*)d_ws;
    u16* Wb   = (u16*)w;  w += sz_Wb;
    u16* Krv  = (u16*)w;  w += sz_Krv;
    u16* hb16 = (u16*)w;

    k_prep<<<1792, 256, 0, stream>>>(x, xT, linear_w, Wb,
                                     log_dt, C_ri, log_A_real, A_imag, Krv);
    k_linear9<<<1024, 256, 0, stream>>>(xT, Wb, linear_b, hb16);
    k_conv_mfma<<<H_, 512, 0, stream>>>(outp, hb16, Krv, Dp, x,
                                        cond, film_w, film_b, res_w);
}